// Round 1
// baseline (540.165 us; speedup 1.0000x reference)
//
#include <hip/hip_runtime.h>
#include <stdint.h>

#define Bn 4
#define Sn 2048
#define En 1024
#define Hn 16
#define Dn 64

typedef unsigned short u16;
typedef short s16x8 __attribute__((ext_vector_type(8)));
typedef float f32x4 __attribute__((ext_vector_type(4)));

#define MFMA16x16x32 __builtin_amdgcn_mfma_f32_16x16x32_bf16

__device__ __forceinline__ u16 f2bf(float f) {
  union { float f; uint32_t u; } v; v.f = f;
  uint32_t u = v.u;
  u += 0x7fffu + ((u >> 16) & 1u);   // round-to-nearest-even
  return (u16)(u >> 16);
}

#define AS1 __attribute__((address_space(1)))
#define AS3 __attribute__((address_space(3)))
__device__ __forceinline__ void gload_lds16(const void* g, void* l) {
  __builtin_amdgcn_global_load_lds((const AS1 uint32_t*)g, (AS3 uint32_t*)l, 16, 0, 0);
}

// ---------------- cast x (fp32 -> bf16), vectorized ----------------
__global__ void cast_x_kernel(const float4* __restrict__ in, ushort4* __restrict__ out, int n4) {
  int i = blockIdx.x * blockDim.x + threadIdx.x;
  if (i >= n4) return;
  float4 v = in[i];
  ushort4 o;
  o.x = f2bf(v.x); o.y = f2bf(v.y); o.z = f2bf(v.z); o.w = f2bf(v.w);
  out[i] = o;
}

// ---- repack Wq/Wk/Wv [H,E,D] -> WallT [3*H*D, E] bf16 (B^T layout), pack bias ----
__global__ void repack_qkv_w(const float* __restrict__ Wq, const float* __restrict__ Wk,
                             const float* __restrict__ Wv, const float* __restrict__ bq,
                             const float* __restrict__ bk, const float* __restrict__ bv,
                             u16* __restrict__ WallT, float* __restrict__ biasA)
{
  int n = blockIdx.x;                 // 0..3071 : sec*1024 + h*64 + d
  int sec = n >> 10;
  int rr = n & 1023;
  int h = rr >> 6, d = rr & 63;
  const float* W  = (sec == 0) ? Wq : (sec == 1) ? Wk : Wv;
  const float* bs = (sec == 0) ? bq : (sec == 1) ? bk : bv;
  for (int e = threadIdx.x; e < En; e += blockDim.x)
    WallT[(size_t)n * En + e] = f2bf(W[((size_t)h * En + e) * Dn + d]);
  if (threadIdx.x == 0) biasA[n] = bs[h * Dn + d];
}

// ---- transpose Wo [H*D, E] -> WoT [E, H*D] bf16 (B^T layout) ----
__global__ void repack_wo(const float* __restrict__ Wo, u16* __restrict__ WoT)
{
  int n = blockIdx.x;                 // output column (E)
  for (int k = threadIdx.x; k < Hn * Dn; k += blockDim.x)
    WoT[(size_t)n * (Hn * Dn) + k] = f2bf(Wo[(size_t)k * En + n]);
}

// ---------------- GEMM: C[M,N] = A[M,K] * Bt[N,K]^T + bias ----------------
// MODE 0: scatter bf16 into Q[B,H,S,D], K[B,H,S,D], Vt[B,H,D,S]
// MODE 1: fp32 row-major output
template<int MODE>
__global__ __launch_bounds__(256) void gemm_bt(
    const u16* __restrict__ A, const u16* __restrict__ Bt,
    const float* __restrict__ bias, int M, int N, int K,
    u16* __restrict__ q_out, u16* __restrict__ k_out, u16* __restrict__ v_out,
    float* __restrict__ f_out)
{
  __shared__ u16 lA[128 * 32];
  __shared__ u16 lB[128 * 32];

  const int tid  = threadIdx.x;
  const int n0   = blockIdx.x * 128;
  const int m0   = blockIdx.y * 128;
  const int w    = tid >> 6;
  const int lane = tid & 63;
  const int quad = lane >> 4;
  const int l15  = lane & 15;
  const int mbase = (w >> 1) * 64;
  const int nbase = (w & 1) * 64;

  f32x4 acc[4][4];
#pragma unroll
  for (int i = 0; i < 4; ++i)
#pragma unroll
    for (int j = 0; j < 4; ++j)
      acc[i][j] = (f32x4){0.f, 0.f, 0.f, 0.f};

  for (int k0 = 0; k0 < K; k0 += 32) {
    __syncthreads();
#pragma unroll
    for (int c = 0; c < 2; ++c) {
      int idx = c * 256 + tid;        // 0..511 ; row = idx>>2, col16B = idx&3
      gload_lds16(A  + (size_t)(m0 + (idx >> 2)) * K + k0 + (idx & 3) * 8, &lA[idx * 8]);
      gload_lds16(Bt + (size_t)(n0 + (idx >> 2)) * K + k0 + (idx & 3) * 8, &lB[idx * 8]);
    }
    __syncthreads();

    s16x8 af[4], bf[4];
#pragma unroll
    for (int t = 0; t < 4; ++t) {
      af[t] = *(const s16x8*)&lA[(mbase + t * 16 + l15) * 32 + quad * 8];
      bf[t] = *(const s16x8*)&lB[(nbase + t * 16 + l15) * 32 + quad * 8];
    }
#pragma unroll
    for (int mt = 0; mt < 4; ++mt)
#pragma unroll
      for (int nt = 0; nt < 4; ++nt)
        acc[mt][nt] = MFMA16x16x32(af[mt], bf[nt], acc[mt][nt], 0, 0, 0);
  }

#pragma unroll
  for (int nt = 0; nt < 4; ++nt) {
    int col = n0 + nbase + nt * 16 + l15;
    float bv = bias[col];
    if (MODE == 0) {
      int sec = col >> 10;
      int rr = col & 1023;
      int h = rr >> 6, d = rr & 63;
#pragma unroll
      for (int mt = 0; mt < 4; ++mt)
#pragma unroll
        for (int r = 0; r < 4; ++r) {
          int row = m0 + mbase + mt * 16 + quad * 4 + r;
          int b = row >> 11, s = row & 2047;
          u16 hv = f2bf(acc[mt][nt][r] + bv);
          if (sec == 0)      q_out[(((size_t)b * Hn + h) * Sn + s) * Dn + d] = hv;
          else if (sec == 1) k_out[(((size_t)b * Hn + h) * Sn + s) * Dn + d] = hv;
          else               v_out[(((size_t)b * Hn + h) * Dn + d) * Sn + s] = hv;
        }
    } else {
#pragma unroll
      for (int mt = 0; mt < 4; ++mt)
#pragma unroll
        for (int r = 0; r < 4; ++r) {
          int row = m0 + mbase + mt * 16 + quad * 4 + r;
          f_out[(size_t)row * N + col] = acc[mt][nt][r] + bv;
        }
    }
  }
}

// ---------------- flash attention (causal, online softmax) ----------------
// grid: (Sn/64, Bn*Hn), 256 threads = 4 waves, wave w handles 16 q-rows
__global__ __launch_bounds__(256) void flash_attn(
    const u16* __restrict__ Qb, const u16* __restrict__ Kb,
    const u16* __restrict__ Vt, u16* __restrict__ conc)
{
  __shared__ u16 lK[64 * 64];            // [kk][d]
  __shared__ u16 lV[64 * 64];            // [d][kk]  (V^T tile)
  __shared__ u16 lP[2][4][16 * 72];      // [buf][wave][q_local][kk_local], stride 72

  const int qt  = blockIdx.x;            // q-tile 0..31
  const int bh  = blockIdx.y;            // 0..63
  const int b   = bh >> 4, h = bh & 15;
  const int tid = threadIdx.x;
  const int w   = tid >> 6;
  const int lane = tid & 63;
  const int quad = lane >> 4;
  const int l15  = lane & 15;
  const int q0   = qt * 64;
  const int Q0   = q0 + w * 16;

  const u16* Qh = Qb + (size_t)bh * Sn * Dn;
  const u16* Kh = Kb + (size_t)bh * Sn * Dn;
  const u16* Vh = Vt + (size_t)bh * Dn * Sn;

  s16x8 aq[2];
#pragma unroll
  for (int c = 0; c < 2; ++c)
    aq[c] = *(const s16x8*)&Qh[(size_t)(Q0 + l15) * Dn + c * 32 + quad * 8];

  f32x4 acc[4];
#pragma unroll
  for (int i = 0; i < 4; ++i) acc[i] = (f32x4){0.f, 0.f, 0.f, 0.f};
  const float NEG_INF = -__builtin_inff();
  float mrow[4], lrow[4];
#pragma unroll
  for (int r = 0; r < 4; ++r) { mrow[r] = NEG_INF; lrow[r] = 0.f; }

  const float scale = 0.125f;            // 1/sqrt(64)

  for (int kt = 0; kt <= qt; ++kt) {
    const int kk0 = kt * 64;
    __syncthreads();
#pragma unroll
    for (int c = 0; c < 2; ++c) {
      int idx = c * 256 + tid;           // 0..511 ; row = idx>>3, col16B = idx&7
      gload_lds16(Kh + (size_t)(kk0 + (idx >> 3)) * Dn + (idx & 7) * 8, &lK[idx * 8]);
      gload_lds16(Vh + (size_t)(idx >> 3) * Sn + kk0 + (idx & 7) * 8, &lV[idx * 8]);
    }
    __syncthreads();

    // S = Q K^T for 16x64 strip: 4 col-tiles x 2 d-chunks
    f32x4 sc[4];
#pragma unroll
    for (int ct = 0; ct < 4; ++ct) {
      s16x8 bk0 = *(const s16x8*)&lK[(ct * 16 + l15) * 64 + quad * 8];
      s16x8 bk1 = *(const s16x8*)&lK[(ct * 16 + l15) * 64 + 32 + quad * 8];
      f32x4 z = (f32x4){0.f, 0.f, 0.f, 0.f};
      z = MFMA16x16x32(aq[0], bk0, z, 0, 0, 0);
      z = MFMA16x16x32(aq[1], bk1, z, 0, 0, 0);
      sc[ct] = z;
    }

    if (kt == qt) {                      // diagonal tile: causal mask
#pragma unroll
      for (int ct = 0; ct < 4; ++ct) {
        int kkg = kk0 + ct * 16 + l15;
#pragma unroll
        for (int r = 0; r < 4; ++r) {
          int qg = Q0 + quad * 4 + r;
          sc[ct][r] = (kkg <= qg) ? sc[ct][r] * scale : NEG_INF;
        }
      }
    } else {
#pragma unroll
      for (int ct = 0; ct < 4; ++ct)
#pragma unroll
        for (int r = 0; r < 4; ++r)
          sc[ct][r] *= scale;
    }

    // row-wise max over this tile (reduce over 16 lanes of the quad)
    float rmax[4], rsum[4];
#pragma unroll
    for (int r = 0; r < 4; ++r)
      rmax[r] = fmaxf(fmaxf(sc[0][r], sc[1][r]), fmaxf(sc[2][r], sc[3][r]));
#pragma unroll
    for (int off = 1; off < 16; off <<= 1)
#pragma unroll
      for (int r = 0; r < 4; ++r)
        rmax[r] = fmaxf(rmax[r], __shfl_xor(rmax[r], off, 64));

    float mnew[4], alpha[4];
#pragma unroll
    for (int r = 0; r < 4; ++r) {
      mnew[r]  = fmaxf(mrow[r], rmax[r]);
      alpha[r] = __expf(mrow[r] - mnew[r]);   // exp(-inf)=0 on first tile
      rsum[r]  = 0.f;
    }
#pragma unroll
    for (int ct = 0; ct < 4; ++ct)
#pragma unroll
      for (int r = 0; r < 4; ++r) {
        float pv = __expf(sc[ct][r] - mnew[r]);  // masked -inf -> 0
        sc[ct][r] = pv;
        rsum[r] += pv;
      }
#pragma unroll
    for (int off = 1; off < 16; off <<= 1)
#pragma unroll
      for (int r = 0; r < 4; ++r)
        rsum[r] += __shfl_xor(rsum[r], off, 64);
#pragma unroll
    for (int r = 0; r < 4; ++r) {
      lrow[r] = lrow[r] * alpha[r] + rsum[r];
      mrow[r] = mnew[r];
    }
#pragma unroll
    for (int dt = 0; dt < 4; ++dt)
#pragma unroll
      for (int r = 0; r < 4; ++r)
        acc[dt][r] *= alpha[r];

    // P: C-layout -> LDS -> A-layout (wave-private region, double-buffered)
    u16* Pw = &lP[kt & 1][w][0];
#pragma unroll
    for (int ct = 0; ct < 4; ++ct)
#pragma unroll
      for (int r = 0; r < 4; ++r)
        Pw[(quad * 4 + r) * 72 + ct * 16 + l15] = f2bf(sc[ct][r]);
    __builtin_amdgcn_s_waitcnt(0xc07f);   // lgkmcnt(0): writes visible wave-wide

    s16x8 ap0 = *(const s16x8*)&Pw[l15 * 72 + quad * 8];
    s16x8 ap1 = *(const s16x8*)&Pw[l15 * 72 + 32 + quad * 8];
#pragma unroll
    for (int dt = 0; dt < 4; ++dt) {
      s16x8 bv0 = *(const s16x8*)&lV[(dt * 16 + l15) * 64 + quad * 8];
      s16x8 bv1 = *(const s16x8*)&lV[(dt * 16 + l15) * 64 + 32 + quad * 8];
      acc[dt] = MFMA16x16x32(ap0, bv0, acc[dt], 0, 0, 0);
      acc[dt] = MFMA16x16x32(ap1, bv1, acc[dt], 0, 0, 0);
    }
  }

  // epilogue: ctx = acc / l, write bf16 into conc [B, S, H*D]
#pragma unroll
  for (int dt = 0; dt < 4; ++dt)
#pragma unroll
    for (int r = 0; r < 4; ++r) {
      int qg = Q0 + quad * 4 + r;
      float v = acc[dt][r] / lrow[r];
      conc[((size_t)b * Sn + qg) * (Hn * Dn) + h * Dn + dt * 16 + l15] = f2bf(v);
    }
}

// ---------------- launch ----------------
extern "C" void kernel_launch(void* const* d_in, const int* in_sizes, int n_in,
                              void* d_out, int out_size, void* d_ws, size_t ws_size,
                              hipStream_t stream)
{
  const float* x  = (const float*)d_in[0];
  const float* Wq = (const float*)d_in[1];
  const float* Wk = (const float*)d_in[2];
  const float* Wv = (const float*)d_in[3];
  const float* bq = (const float*)d_in[4];
  const float* bk = (const float*)d_in[5];
  const float* bv = (const float*)d_in[6];
  const float* Wo = (const float*)d_in[7];
  const float* bo = (const float*)d_in[8];
  float* out = (float*)d_out;

  char* p = (char*)d_ws;
  u16* xb    = (u16*)p; p += (size_t)Bn * Sn * En * sizeof(u16);        // 16.8 MB
  u16* WallT = (u16*)p; p += (size_t)3 * Hn * Dn * En * sizeof(u16);    // 6.3 MB
  u16* WoT   = (u16*)p; p += (size_t)En * Hn * Dn * sizeof(u16);        // 2.1 MB
  float* biasA = (float*)p; p += (size_t)3 * Hn * Dn * sizeof(float);   // 12 KB
  u16* Qb    = (u16*)p; p += (size_t)Bn * Hn * Sn * Dn * sizeof(u16);   // 16.8 MB
  u16* Kb    = (u16*)p; p += (size_t)Bn * Hn * Sn * Dn * sizeof(u16);   // 16.8 MB
  u16* Vt    = (u16*)p; p += (size_t)Bn * Hn * Dn * Sn * sizeof(u16);   // 16.8 MB
  u16* conc  = (u16*)p; p += (size_t)Bn * Sn * Hn * Dn * sizeof(u16);   // 16.8 MB

  int n4 = Bn * Sn * En / 4;
  cast_x_kernel<<<(n4 + 255) / 256, 256, 0, stream>>>((const float4*)x, (ushort4*)xb, n4);
  repack_qkv_w<<<3 * Hn * Dn, 256, 0, stream>>>(Wq, Wk, Wv, bq, bk, bv, WallT, biasA);
  repack_wo<<<En, 256, 0, stream>>>(Wo, WoT);

  // QKV: [8192,1024] x [1024,3072] -> scatter Q/K/V^T
  gemm_bt<0><<<dim3(3 * Hn * Dn / 128, Bn * Sn / 128), 256, 0, stream>>>(
      xb, WallT, biasA, Bn * Sn, 3 * Hn * Dn, En, Qb, Kb, Vt, nullptr);

  flash_attn<<<dim3(Sn / 64, Bn * Hn), 256, 0, stream>>>(Qb, Kb, Vt, conc);

  // out: [8192,1024] x [1024,1024] + bo -> fp32
  gemm_bt<1><<<dim3(En / 128, Bn * Sn / 128), 256, 0, stream>>>(
      conc, WoT, bo, Bn * Sn, En, Hn * Dn, nullptr, nullptr, nullptr, out);
}

// Round 2
// 494.564 us; speedup vs baseline: 1.0922x; 1.0922x over previous
//
#include <hip/hip_runtime.h>
#include <stdint.h>

#define Bn 4
#define Sn 2048
#define En 1024
#define Hn 16
#define Dn 64

typedef unsigned short u16;
typedef short s16x8 __attribute__((ext_vector_type(8)));
typedef float f32x4 __attribute__((ext_vector_type(4)));

#define MFMA16x16x32 __builtin_amdgcn_mfma_f32_16x16x32_bf16

__device__ __forceinline__ u16 f2bf(float f) {
  union { float f; uint32_t u; } v; v.f = f;
  uint32_t u = v.u;
  u += 0x7fffu + ((u >> 16) & 1u);   // round-to-nearest-even
  return (u16)(u >> 16);
}

#define AS1 __attribute__((address_space(1)))
#define AS3 __attribute__((address_space(3)))
__device__ __forceinline__ void gload_lds16(const void* g, void* l) {
  __builtin_amdgcn_global_load_lds((const AS1 uint32_t*)g, (AS3 uint32_t*)l, 16, 0, 0);
}

// ---------------- cast x (fp32 -> bf16), vectorized ----------------
__global__ void cast_x_kernel(const float4* __restrict__ in, ushort4* __restrict__ out, int n4) {
  int i = blockIdx.x * blockDim.x + threadIdx.x;
  if (i >= n4) return;
  float4 v = in[i];
  ushort4 o;
  o.x = f2bf(v.x); o.y = f2bf(v.y); o.z = f2bf(v.z); o.w = f2bf(v.w);
  out[i] = o;
}

// ---- repack Wq/Wk/Wv [H,E,D] -> WallT [3*H*D, E] bf16 (B^T layout), pack bias ----
__global__ void repack_qkv_w(const float* __restrict__ Wq, const float* __restrict__ Wk,
                             const float* __restrict__ Wv, const float* __restrict__ bq,
                             const float* __restrict__ bk, const float* __restrict__ bv,
                             u16* __restrict__ WallT, float* __restrict__ biasA)
{
  int n = blockIdx.x;                 // 0..3071 : sec*1024 + h*64 + d
  int sec = n >> 10;
  int rr = n & 1023;
  int h = rr >> 6, d = rr & 63;
  const float* W  = (sec == 0) ? Wq : (sec == 1) ? Wk : Wv;
  const float* bs = (sec == 0) ? bq : (sec == 1) ? bk : bv;
  for (int e = threadIdx.x; e < En; e += blockDim.x)
    WallT[(size_t)n * En + e] = f2bf(W[((size_t)h * En + e) * Dn + d]);
  if (threadIdx.x == 0) biasA[n] = bs[h * Dn + d];
}

// ---- transpose Wo [H*D, E] -> WoT [E, H*D] bf16 (B^T layout) ----
__global__ void repack_wo(const float* __restrict__ Wo, u16* __restrict__ WoT)
{
  int n = blockIdx.x;                 // output column (E)
  for (int k = threadIdx.x; k < Hn * Dn; k += blockDim.x)
    WoT[(size_t)n * (Hn * Dn) + k] = f2bf(Wo[(size_t)k * En + n]);
}

// ---------------- GEMM: C[M,N] = A[M,K] * Bt[N,K]^T + bias ----------------
// LDS tiles XOR-swizzled: 16B segment s of row r stored at segment s^((r>>1)&3)
// MODE 0: bf16 out -> Q[B,H,S,D], K[B,H,S,D] direct; V^T[B,H,D,S] via LDS transpose
// MODE 1: fp32 row-major output
template<int MODE>
__global__ __launch_bounds__(256) void gemm_bt(
    const u16* __restrict__ A, const u16* __restrict__ Bt,
    const float* __restrict__ bias, int M, int N, int K,
    u16* __restrict__ q_out, u16* __restrict__ k_out, u16* __restrict__ v_out,
    float* __restrict__ f_out)
{
  extern __shared__ __align__(16) u16 smem[];
  u16* lA = smem;                // 128 x 32
  u16* lB = smem + 128 * 32;     // 128 x 32

  const int tid  = threadIdx.x;
  const int n0   = blockIdx.x * 128;
  const int m0   = blockIdx.y * 128;
  const int w    = tid >> 6;
  const int lane = tid & 63;
  const int quad = lane >> 4;
  const int l15  = lane & 15;
  const int mbase = (w >> 1) * 64;
  const int nbase = (w & 1) * 64;
  const int swz   = (quad ^ ((l15 >> 1) & 3)) * 8;   // swizzled 16B segment for frag reads

  f32x4 acc[4][4];
#pragma unroll
  for (int i = 0; i < 4; ++i)
#pragma unroll
    for (int j = 0; j < 4; ++j)
      acc[i][j] = (f32x4){0.f, 0.f, 0.f, 0.f};

  for (int k0 = 0; k0 < K; k0 += 32) {
    __syncthreads();
#pragma unroll
    for (int c = 0; c < 2; ++c) {
      int idx = c * 256 + tid;        // 0..511
      int row = idx >> 2, sl = idx & 3;
      int sg = sl ^ ((row >> 1) & 3); // global 16B segment to fetch
      gload_lds16(A  + (size_t)(m0 + row) * K + k0 + sg * 8, &lA[idx * 8]);
      gload_lds16(Bt + (size_t)(n0 + row) * K + k0 + sg * 8, &lB[idx * 8]);
    }
    __syncthreads();

    s16x8 af[4], bf[4];
#pragma unroll
    for (int t = 0; t < 4; ++t) {
      af[t] = *(const s16x8*)&lA[(mbase + t * 16 + l15) * 32 + swz];
      bf[t] = *(const s16x8*)&lB[(nbase + t * 16 + l15) * 32 + swz];
    }
#pragma unroll
    for (int mt = 0; mt < 4; ++mt)
#pragma unroll
      for (int nt = 0; nt < 4; ++nt)
        acc[mt][nt] = MFMA16x16x32(af[mt], bf[nt], acc[mt][nt], 0, 0, 0);
  }

  if (MODE == 0) {
    int sec = n0 >> 10;               // block-uniform (sec spans 1024 = 8 n-tiles)
    if (sec < 2) {
#pragma unroll
      for (int nt = 0; nt < 4; ++nt) {
        int col = n0 + nbase + nt * 16 + l15;
        float bv = bias[col];
        int rr = col & 1023;
        int h = rr >> 6, d = rr & 63;
        u16* dst = (sec == 0) ? q_out : k_out;
#pragma unroll
        for (int mt = 0; mt < 4; ++mt)
#pragma unroll
          for (int r = 0; r < 4; ++r) {
            int row = m0 + mbase + mt * 16 + quad * 4 + r;
            int b = row >> 11, s = row & 2047;
            dst[(((size_t)b * Hn + h) * Sn + s) * Dn + d] = f2bf(acc[mt][nt][r] + bv);
          }
      }
    } else {
      // V: stage C-tile transposed in LDS, then coalesced V^T stores along S
      u16* lC = smem + 128 * 64;      // 128 cols x 136 (pad: 272B rows, 16B aligned)
#pragma unroll
      for (int nt = 0; nt < 4; ++nt) {
        int cl = nbase + nt * 16 + l15;
        float bv = bias[n0 + cl];
#pragma unroll
        for (int mt = 0; mt < 4; ++mt)
#pragma unroll
          for (int r = 0; r < 4; ++r) {
            int rowl = mbase + mt * 16 + quad * 4 + r;
            lC[cl * 136 + rowl] = f2bf(acc[mt][nt][r] + bv);
          }
      }
      __syncthreads();
      int c  = tid >> 1, hh = tid & 1;
      int col = n0 + c;
      int h = (col >> 6) & 15, d = col & 63;
      int b = m0 >> 11;
      int s0 = (m0 & 2047) + hh * 64;
      const uint4* src = (const uint4*)&lC[c * 136 + hh * 64];
      uint4* dst = (uint4*)&v_out[(((size_t)b * Hn + h) * Dn + d) * Sn + s0];
#pragma unroll
      for (int i = 0; i < 8; ++i) dst[i] = src[i];
    }
  } else {
#pragma unroll
    for (int nt = 0; nt < 4; ++nt) {
      int col = n0 + nbase + nt * 16 + l15;
      float bv = bias[col];
#pragma unroll
      for (int mt = 0; mt < 4; ++mt)
#pragma unroll
        for (int r = 0; r < 4; ++r) {
          int row = m0 + mbase + mt * 16 + quad * 4 + r;
          f_out[(size_t)row * N + col] = acc[mt][nt][r] + bv;
        }
    }
  }
}

// ---------------- flash attention (causal, online softmax) ----------------
// grid: (Sn/128, Bn*Hn), 256 threads = 4 waves.
// Block q-tile = 128 rows; wave w owns rows [w*16,w*16+16) and [64+w*16, 64+w*16+16)
// K/V tiles (64 kk) XOR-swizzled in LDS (seg s at s^(row&7)) -> conflict-free b128 reads.
__global__ __launch_bounds__(256) void flash_attn(
    const u16* __restrict__ Qb, const u16* __restrict__ Kb,
    const u16* __restrict__ Vt, u16* __restrict__ conc)
{
  __shared__ __align__(16) u16 lK[64 * 64];          // [kk][d] swizzled
  __shared__ __align__(16) u16 lV[64 * 64];          // [d][kk] swizzled
  __shared__ __align__(16) u16 lP[2][4][2][16 * 72]; // [buf][wave][mtile][q][kk]

  const int qt  = (gridDim.x - 1) - blockIdx.x;      // heavy q-tiles dispatch first
  const int bh  = blockIdx.y;
  const int b   = bh >> 4, h = bh & 15;
  const int tid = threadIdx.x;
  const int w   = tid >> 6;
  const int lane = tid & 63;
  const int quad = lane >> 4;
  const int l15  = lane & 15;
  const int q0   = qt * 128;

  const u16* Qh = Qb + (size_t)bh * Sn * Dn;
  const u16* Kh = Kb + (size_t)bh * Sn * Dn;
  const u16* Vh = Vt + (size_t)bh * Dn * Sn;

  const int Q0m[2] = { q0 + w * 16, q0 + 64 + w * 16 };

  s16x8 aq[2][2];
#pragma unroll
  for (int m = 0; m < 2; ++m)
#pragma unroll
    for (int c = 0; c < 2; ++c)
      aq[m][c] = *(const s16x8*)&Qh[(size_t)(Q0m[m] + l15) * Dn + c * 32 + quad * 8];

  f32x4 acc[2][4];
#pragma unroll
  for (int m = 0; m < 2; ++m)
#pragma unroll
    for (int i = 0; i < 4; ++i) acc[m][i] = (f32x4){0.f, 0.f, 0.f, 0.f};
  const float NEG_INF = -__builtin_inff();
  float mrow[2][4], lrow[2][4];
#pragma unroll
  for (int m = 0; m < 2; ++m)
#pragma unroll
    for (int r = 0; r < 4; ++r) { mrow[m][r] = NEG_INF; lrow[m][r] = 0.f; }

  // log2-domain softmax: S*scale*log2(e), exp via exp2
  const float qscale = 0.125f * 1.44269504088896f;
  const int rx = (l15 & 7) * 8;            // row-dependent part of swizzle (r&7 == l15&7)
  const int sw0 = (quad ^ (l15 & 7)) * 8;        // seg quad
  const int sw1 = ((quad + 4) ^ (l15 & 7)) * 8;  // seg quad+4
  (void)rx;

  const int ntiles = 2 * qt + 2;
  for (int kt = 0; kt < ntiles; ++kt) {
    const int kk0 = kt * 64;
    __syncthreads();
#pragma unroll
    for (int c = 0; c < 2; ++c) {
      int idx = c * 256 + tid;             // 0..511
      int row = idx >> 3, sl = idx & 7;
      int sg = sl ^ (row & 7);             // global 16B segment to fetch
      gload_lds16(Kh + (size_t)(kk0 + row) * Dn + sg * 8, &lK[idx * 8]);
      gload_lds16(Vh + (size_t)row * Sn + kk0 + sg * 8, &lV[idx * 8]);
    }
    __syncthreads();

#pragma unroll
    for (int m = 0; m < 2; ++m) {
      const int Q0 = Q0m[m];
      if (kk0 >= Q0 + 16) continue;        // sub-tile fully masked (wave-uniform)

      // S = Q K^T : 4 col-tiles x 2 d-chunks
      f32x4 sc[4];
#pragma unroll
      for (int ct = 0; ct < 4; ++ct) {
        s16x8 bk0 = *(const s16x8*)&lK[(ct * 16 + l15) * 64 + sw0];
        s16x8 bk1 = *(const s16x8*)&lK[(ct * 16 + l15) * 64 + sw1];
        f32x4 z = (f32x4){0.f, 0.f, 0.f, 0.f};
        z = MFMA16x16x32(aq[m][0], bk0, z, 0, 0, 0);
        z = MFMA16x16x32(aq[m][1], bk1, z, 0, 0, 0);
        sc[ct] = z;
      }

      if (kk0 + 63 > Q0) {                 // diagonal region: causal mask
#pragma unroll
        for (int ct = 0; ct < 4; ++ct) {
          int kkg = kk0 + ct * 16 + l15;
#pragma unroll
          for (int r = 0; r < 4; ++r) {
            int qg = Q0 + quad * 4 + r;
            sc[ct][r] = (kkg <= qg) ? sc[ct][r] * qscale : NEG_INF;
          }
        }
      } else {
#pragma unroll
        for (int ct = 0; ct < 4; ++ct)
#pragma unroll
          for (int r = 0; r < 4; ++r)
            sc[ct][r] *= qscale;
      }

      float rmax[4], rsum[4];
#pragma unroll
      for (int r = 0; r < 4; ++r)
        rmax[r] = fmaxf(fmaxf(sc[0][r], sc[1][r]), fmaxf(sc[2][r], sc[3][r]));
#pragma unroll
      for (int off = 1; off < 16; off <<= 1)
#pragma unroll
        for (int r = 0; r < 4; ++r)
          rmax[r] = fmaxf(rmax[r], __shfl_xor(rmax[r], off, 64));

      float mnew[4], alpha[4];
#pragma unroll
      for (int r = 0; r < 4; ++r) {
        mnew[r]  = fmaxf(mrow[m][r], rmax[r]);
        alpha[r] = exp2f(mrow[m][r] - mnew[r]);
        rsum[r]  = 0.f;
      }
#pragma unroll
      for (int ct = 0; ct < 4; ++ct)
#pragma unroll
        for (int r = 0; r < 4; ++r) {
          float pv = exp2f(sc[ct][r] - mnew[r]);
          sc[ct][r] = pv;
          rsum[r] += pv;
        }
#pragma unroll
      for (int off = 1; off < 16; off <<= 1)
#pragma unroll
        for (int r = 0; r < 4; ++r)
          rsum[r] += __shfl_xor(rsum[r], off, 64);
#pragma unroll
      for (int r = 0; r < 4; ++r) {
        lrow[m][r] = lrow[m][r] * alpha[r] + rsum[r];
        mrow[m][r] = mnew[r];
      }
#pragma unroll
      for (int dt = 0; dt < 4; ++dt)
#pragma unroll
        for (int r = 0; r < 4; ++r)
          acc[m][dt][r] *= alpha[r];

      // P: C-layout -> LDS -> A-layout (wave-private, double-buffered on kt)
      u16* Pw = &lP[kt & 1][w][m][0];
#pragma unroll
      for (int ct = 0; ct < 4; ++ct)
#pragma unroll
        for (int r = 0; r < 4; ++r)
          Pw[(quad * 4 + r) * 72 + ct * 16 + l15] = f2bf(sc[ct][r]);
      __builtin_amdgcn_s_waitcnt(0xc07f);  // lgkmcnt(0)

      s16x8 ap0 = *(const s16x8*)&Pw[l15 * 72 + quad * 8];
      s16x8 ap1 = *(const s16x8*)&Pw[l15 * 72 + 32 + quad * 8];
#pragma unroll
      for (int dt = 0; dt < 4; ++dt) {
        s16x8 bv0 = *(const s16x8*)&lV[(dt * 16 + l15) * 64 + sw0];
        s16x8 bv1 = *(const s16x8*)&lV[(dt * 16 + l15) * 64 + sw1];
        acc[m][dt] = MFMA16x16x32(ap0, bv0, acc[m][dt], 0, 0, 0);
        acc[m][dt] = MFMA16x16x32(ap1, bv1, acc[m][dt], 0, 0, 0);
      }
    }
  }

  // epilogue: ctx = acc / l -> conc [B, S, H*D] bf16
#pragma unroll
  for (int m = 0; m < 2; ++m)
#pragma unroll
    for (int r = 0; r < 4; ++r) {
      float inv = 1.0f / lrow[m][r];
      int qg = Q0m[m] + quad * 4 + r;
#pragma unroll
      for (int dt = 0; dt < 4; ++dt)
        conc[((size_t)b * Sn + qg) * (Hn * Dn) + h * Dn + dt * 16 + l15] =
            f2bf(acc[m][dt][r] * inv);
    }
}

// ---------------- launch ----------------
extern "C" void kernel_launch(void* const* d_in, const int* in_sizes, int n_in,
                              void* d_out, int out_size, void* d_ws, size_t ws_size,
                              hipStream_t stream)
{
  const float* x  = (const float*)d_in[0];
  const float* Wq = (const float*)d_in[1];
  const float* Wk = (const float*)d_in[2];
  const float* Wv = (const float*)d_in[3];
  const float* bq = (const float*)d_in[4];
  const float* bk = (const float*)d_in[5];
  const float* bv = (const float*)d_in[6];
  const float* Wo = (const float*)d_in[7];
  const float* bo = (const float*)d_in[8];
  float* out = (float*)d_out;

  char* p = (char*)d_ws;
  u16* xb    = (u16*)p; p += (size_t)Bn * Sn * En * sizeof(u16);
  u16* WallT = (u16*)p; p += (size_t)3 * Hn * Dn * En * sizeof(u16);
  u16* WoT   = (u16*)p; p += (size_t)En * Hn * Dn * sizeof(u16);
  float* biasA = (float*)p; p += (size_t)3 * Hn * Dn * sizeof(float);
  u16* Qb    = (u16*)p; p += (size_t)Bn * Hn * Sn * Dn * sizeof(u16);
  u16* Kb    = (u16*)p; p += (size_t)Bn * Hn * Sn * Dn * sizeof(u16);
  u16* Vt    = (u16*)p; p += (size_t)Bn * Hn * Dn * Sn * sizeof(u16);
  u16* conc  = (u16*)p; p += (size_t)Bn * Sn * Hn * Dn * sizeof(u16);

  int n4 = Bn * Sn * En / 4;
  cast_x_kernel<<<(n4 + 255) / 256, 256, 0, stream>>>((const float4*)x, (ushort4*)xb, n4);
  repack_qkv_w<<<3 * Hn * Dn, 256, 0, stream>>>(Wq, Wk, Wv, bq, bk, bv, WallT, biasA);
  repack_wo<<<En, 256, 0, stream>>>(Wo, WoT);

  // QKV: [8192,1024] x [1024,3072] -> Q/K direct, V^T via LDS transpose
  size_t smem0 = 128 * 64 * sizeof(u16) + 128 * 136 * sizeof(u16);  // lA+lB + lC
  gemm_bt<0><<<dim3(3 * Hn * Dn / 128, Bn * Sn / 128), 256, smem0, stream>>>(
      xb, WallT, biasA, Bn * Sn, 3 * Hn * Dn, En, Qb, Kb, Vt, nullptr);

  flash_attn<<<dim3(Sn / 128, Bn * Hn), 256, 0, stream>>>(Qb, Kb, Vt, conc);

  // out: [8192,1024] x [1024,1024] + bo -> fp32
  size_t smem1 = 128 * 64 * sizeof(u16);
  gemm_bt<1><<<dim3(En / 128, Bn * Sn / 128), 256, smem1, stream>>>(
      conc, WoT, bo, Bn * Sn, En, Hn * Dn, nullptr, nullptr, nullptr, out);
}

// Round 3
// 433.983 us; speedup vs baseline: 1.2447x; 1.1396x over previous
//
#include <hip/hip_runtime.h>
#include <stdint.h>

#define Bn 4
#define Sn 2048
#define En 1024
#define Hn 16
#define Dn 64

typedef unsigned short u16;
typedef short s16x8 __attribute__((ext_vector_type(8)));
typedef float f32x4 __attribute__((ext_vector_type(4)));

#define MFMA16x16x32 __builtin_amdgcn_mfma_f32_16x16x32_bf16

__device__ __forceinline__ u16 f2bf(float f) {
  union { float f; uint32_t u; } v; v.f = f;
  uint32_t u = v.u;
  u += 0x7fffu + ((u >> 16) & 1u);   // round-to-nearest-even
  return (u16)(u >> 16);
}

#define AS1 __attribute__((address_space(1)))
#define AS3 __attribute__((address_space(3)))
__device__ __forceinline__ void gload_lds16(const void* g, void* l) {
  __builtin_amdgcn_global_load_lds((const AS1 uint32_t*)g, (AS3 uint32_t*)l, 16, 0, 0);
}

// ---------------- cast x (fp32 -> bf16), vectorized ----------------
__global__ void cast_x_kernel(const float4* __restrict__ in, ushort4* __restrict__ out, int n4) {
  int i = blockIdx.x * blockDim.x + threadIdx.x;
  if (i >= n4) return;
  float4 v = in[i];
  ushort4 o;
  o.x = f2bf(v.x); o.y = f2bf(v.y); o.z = f2bf(v.z); o.w = f2bf(v.w);
  out[i] = o;
}

// ---- repack Wq/Wk/Wv [H,E,D] -> WallT [3*H*D, E] bf16 (B^T layout), pack bias ----
__global__ void repack_qkv_w(const float* __restrict__ Wq, const float* __restrict__ Wk,
                             const float* __restrict__ Wv, const float* __restrict__ bq,
                             const float* __restrict__ bk, const float* __restrict__ bv,
                             u16* __restrict__ WallT, float* __restrict__ biasA)
{
  int n = blockIdx.x;                 // 0..3071 : sec*1024 + h*64 + d
  int sec = n >> 10;
  int rr = n & 1023;
  int h = rr >> 6, d = rr & 63;
  const float* W  = (sec == 0) ? Wq : (sec == 1) ? Wk : Wv;
  const float* bs = (sec == 0) ? bq : (sec == 1) ? bk : bv;
  for (int e = threadIdx.x; e < En; e += blockDim.x)
    WallT[(size_t)n * En + e] = f2bf(W[((size_t)h * En + e) * Dn + d]);
  if (threadIdx.x == 0) biasA[n] = bs[h * Dn + d];
}

// ---- transpose Wo [H*D, E] -> WoT [E, H*D] bf16 (B^T layout) ----
__global__ void repack_wo(const float* __restrict__ Wo, u16* __restrict__ WoT)
{
  int n = blockIdx.x;                 // output column (E)
  for (int k = threadIdx.x; k < Hn * Dn; k += blockDim.x)
    WoT[(size_t)n * (Hn * Dn) + k] = f2bf(Wo[(size_t)k * En + n]);
}

// ---------------- GEMM: C[M,N] = A[M,K] * Bt[N,K]^T + bias ----------------
// LDS tiles XOR-swizzled: 16B segment s of row r stored at segment s^((r>>1)&3)
// MODE 0: bf16 out -> Q[B,H,S,D], K[B,H,S,D] direct; V^T[B,H,D,S] via LDS transpose
// MODE 1: fp32 row-major output
template<int MODE>
__global__ __launch_bounds__(256) void gemm_bt(
    const u16* __restrict__ A, const u16* __restrict__ Bt,
    const float* __restrict__ bias, int M, int N, int K,
    u16* __restrict__ q_out, u16* __restrict__ k_out, u16* __restrict__ v_out,
    float* __restrict__ f_out)
{
  extern __shared__ __align__(16) u16 smem[];
  u16* lA = smem;                // 128 x 32
  u16* lB = smem + 128 * 32;     // 128 x 32

  const int tid  = threadIdx.x;
  const int n0   = blockIdx.x * 128;
  const int m0   = blockIdx.y * 128;
  const int w    = tid >> 6;
  const int lane = tid & 63;
  const int quad = lane >> 4;
  const int l15  = lane & 15;
  const int mbase = (w >> 1) * 64;
  const int nbase = (w & 1) * 64;
  const int swz   = (quad ^ ((l15 >> 1) & 3)) * 8;   // swizzled 16B segment for frag reads

  f32x4 acc[4][4];
#pragma unroll
  for (int i = 0; i < 4; ++i)
#pragma unroll
    for (int j = 0; j < 4; ++j)
      acc[i][j] = (f32x4){0.f, 0.f, 0.f, 0.f};

  for (int k0 = 0; k0 < K; k0 += 32) {
    __syncthreads();
#pragma unroll
    for (int c = 0; c < 2; ++c) {
      int idx = c * 256 + tid;        // 0..511
      int row = idx >> 2, sl = idx & 3;
      int sg = sl ^ ((row >> 1) & 3); // global 16B segment to fetch
      gload_lds16(A  + (size_t)(m0 + row) * K + k0 + sg * 8, &lA[idx * 8]);
      gload_lds16(Bt + (size_t)(n0 + row) * K + k0 + sg * 8, &lB[idx * 8]);
    }
    __syncthreads();

    s16x8 af[4], bf[4];
#pragma unroll
    for (int t = 0; t < 4; ++t) {
      af[t] = *(const s16x8*)&lA[(mbase + t * 16 + l15) * 32 + swz];
      bf[t] = *(const s16x8*)&lB[(nbase + t * 16 + l15) * 32 + swz];
    }
#pragma unroll
    for (int mt = 0; mt < 4; ++mt)
#pragma unroll
      for (int nt = 0; nt < 4; ++nt)
        acc[mt][nt] = MFMA16x16x32(af[mt], bf[nt], acc[mt][nt], 0, 0, 0);
  }

  if (MODE == 0) {
    int sec = n0 >> 10;               // block-uniform (sec spans 1024 = 8 n-tiles)
    if (sec < 2) {
#pragma unroll
      for (int nt = 0; nt < 4; ++nt) {
        int col = n0 + nbase + nt * 16 + l15;
        float bv = bias[col];
        int rr = col & 1023;
        int h = rr >> 6, d = rr & 63;
        u16* dst = (sec == 0) ? q_out : k_out;
#pragma unroll
        for (int mt = 0; mt < 4; ++mt)
#pragma unroll
          for (int r = 0; r < 4; ++r) {
            int row = m0 + mbase + mt * 16 + quad * 4 + r;
            int b = row >> 11, s = row & 2047;
            dst[(((size_t)b * Hn + h) * Sn + s) * Dn + d] = f2bf(acc[mt][nt][r] + bv);
          }
      }
    } else {
      // V: stage C-tile transposed in LDS, then coalesced V^T stores along S
      u16* lC = smem + 128 * 64;      // 128 cols x 136
#pragma unroll
      for (int nt = 0; nt < 4; ++nt) {
        int cl = nbase + nt * 16 + l15;
        float bv = bias[n0 + cl];
#pragma unroll
        for (int mt = 0; mt < 4; ++mt)
#pragma unroll
          for (int r = 0; r < 4; ++r) {
            int rowl = mbase + mt * 16 + quad * 4 + r;
            lC[cl * 136 + rowl] = f2bf(acc[mt][nt][r] + bv);
          }
      }
      __syncthreads();
      int c  = tid >> 1, hh = tid & 1;
      int col = n0 + c;
      int h = (col >> 6) & 15, d = col & 63;
      int b = m0 >> 11;
      int s0 = (m0 & 2047) + hh * 64;
      const uint4* src = (const uint4*)&lC[c * 136 + hh * 64];
      uint4* dst = (uint4*)&v_out[(((size_t)b * Hn + h) * Dn + d) * Sn + s0];
#pragma unroll
      for (int i = 0; i < 8; ++i) dst[i] = src[i];
    }
  } else {
#pragma unroll
    for (int nt = 0; nt < 4; ++nt) {
      int col = n0 + nbase + nt * 16 + l15;
      float bv = bias[col];
#pragma unroll
      for (int mt = 0; mt < 4; ++mt)
#pragma unroll
        for (int r = 0; r < 4; ++r) {
          int row = m0 + mbase + mt * 16 + quad * 4 + r;
          f_out[(size_t)row * N + col] = acc[mt][nt][r] + bv;
        }
    }
  }
}

// ---------------- flash attention v3 ----------------
// grid: (Sn/128, Bn*Hn), 256 threads = 4 waves; wave w owns q-rows w*16.. and 64+w*16..
// S^T orientation: S^T = MFMA(K-frag, Q-frag) -> lane l15 = q-row, regs = 16 k-values.
// O^T accumulation: O^T = MFMA(V^T-frag, P-frag) -> alpha/l are per-lane scalars.
// K/V LDS double-buffered; stage(kt+1) issued right after the barrier -> latency hidden.
__global__ __launch_bounds__(256) void flash_attn(
    const u16* __restrict__ Qb, const u16* __restrict__ Kb,
    const u16* __restrict__ Vt, u16* __restrict__ conc)
{
  __shared__ __align__(16) u16 lK[2][64 * 64];   // [buf][kk][d] swizzled
  __shared__ __align__(16) u16 lV[2][64 * 64];   // [buf][d][kk] swizzled
  __shared__ __align__(16) u16 lP[4][16 * 72];   // [wave][q][kk] (reused across m, kt)

  const int qt  = (gridDim.x - 1) - blockIdx.x;  // heavy q-tiles dispatch first
  const int bh  = blockIdx.y;
  const int b   = bh >> 4, h = bh & 15;
  const int tid = threadIdx.x;
  const int w   = tid >> 6;
  const int lane = tid & 63;
  const int quad = lane >> 4;
  const int l15  = lane & 15;
  const int q0   = qt * 128;

  const u16* Qh = Qb + (size_t)bh * Sn * Dn;
  const u16* Kh = Kb + (size_t)bh * Sn * Dn;
  const u16* Vh = Vt + (size_t)bh * Dn * Sn;

  const int Q0m[2] = { q0 + w * 16, q0 + 64 + w * 16 };

  s16x8 aq[2][2];                      // Q fragments (B operand)
#pragma unroll
  for (int m = 0; m < 2; ++m)
#pragma unroll
    for (int c = 0; c < 2; ++c)
      aq[m][c] = *(const s16x8*)&Qh[(size_t)(Q0m[m] + l15) * Dn + c * 32 + quad * 8];

  f32x4 acc[2][4];                     // O^T tiles: row d = dt*16+quad*4+r, col q = l15
#pragma unroll
  for (int m = 0; m < 2; ++m)
#pragma unroll
    for (int i = 0; i < 4; ++i) acc[m][i] = (f32x4){0.f, 0.f, 0.f, 0.f};
  const float NEG_INF = -__builtin_inff();
  float mrow[2] = {NEG_INF, NEG_INF};
  float lrow[2] = {0.f, 0.f};

  const float qscale = 0.125f * 1.44269504088896f;   // scale * log2(e)
  const int sw0 = (quad ^ (l15 & 7)) * 8;
  const int sw1 = ((quad + 4) ^ (l15 & 7)) * 8;

  const int ntiles = 2 * qt + 2;

  auto stage = [&](int kt) {
    int bufb = kt & 1;
    int kk0 = kt * 64;
#pragma unroll
    for (int c = 0; c < 2; ++c) {
      int idx = c * 256 + tid;         // 0..511
      int row = idx >> 3, sl = idx & 7;
      int sg = sl ^ (row & 7);
      gload_lds16(Kh + (size_t)(kk0 + row) * Dn + sg * 8, &lK[bufb][idx * 8]);
      gload_lds16(Vh + (size_t)row * Sn + kk0 + sg * 8, &lV[bufb][idx * 8]);
    }
  };

  stage(0);
  for (int kt = 0; kt < ntiles; ++kt) {
    const int kk0 = kt * 64;
    __syncthreads();                   // drains stage(kt); issued one compute ago
    if (kt + 1 < ntiles) stage(kt + 1);
    const u16* cK = lK[kt & 1];
    const u16* cV = lV[kt & 1];

#pragma unroll
    for (int m = 0; m < 2; ++m) {
      const int Q0 = Q0m[m];
      if (kk0 >= Q0 + 16) continue;    // sub-tile fully masked (wave-uniform)

      // S^T = K·Q^T : lane holds q-row (l15), k = kk0 + ct*16 + quad*4 + r
      f32x4 sc[4];
#pragma unroll
      for (int ct = 0; ct < 4; ++ct) {
        s16x8 bk0 = *(const s16x8*)&cK[(ct * 16 + l15) * 64 + sw0];
        s16x8 bk1 = *(const s16x8*)&cK[(ct * 16 + l15) * 64 + sw1];
        f32x4 z = (f32x4){0.f, 0.f, 0.f, 0.f};
        z = MFMA16x16x32(bk0, aq[m][0], z, 0, 0, 0);
        z = MFMA16x16x32(bk1, aq[m][1], z, 0, 0, 0);
        sc[ct] = z;
      }

      const int qg = Q0 + l15;
      if (kk0 + 63 > Q0) {             // diagonal region: causal mask
#pragma unroll
        for (int ct = 0; ct < 4; ++ct)
#pragma unroll
          for (int r = 0; r < 4; ++r) {
            int kkg = kk0 + ct * 16 + quad * 4 + r;
            sc[ct][r] = (kkg <= qg) ? sc[ct][r] * qscale : NEG_INF;
          }
      } else {
#pragma unroll
        for (int ct = 0; ct < 4; ++ct)
#pragma unroll
          for (int r = 0; r < 4; ++r)
            sc[ct][r] *= qscale;
      }

      // row max: 15 local ops + 2 shuffles
      float rmax = sc[0][0];
#pragma unroll
      for (int ct = 0; ct < 4; ++ct)
#pragma unroll
        for (int r = 0; r < 4; ++r) rmax = fmaxf(rmax, sc[ct][r]);
      rmax = fmaxf(rmax, __shfl_xor(rmax, 16, 64));
      rmax = fmaxf(rmax, __shfl_xor(rmax, 32, 64));

      float mnew  = fmaxf(mrow[m], rmax);
      float alpha = exp2f(mrow[m] - mnew);
      float rsum  = 0.f;
#pragma unroll
      for (int ct = 0; ct < 4; ++ct)
#pragma unroll
        for (int r = 0; r < 4; ++r) {
          float pv = exp2f(sc[ct][r] - mnew);
          sc[ct][r] = pv;
          rsum += pv;
        }
      rsum += __shfl_xor(rsum, 16, 64);
      rsum += __shfl_xor(rsum, 32, 64);
      lrow[m] = lrow[m] * alpha + rsum;
      mrow[m] = mnew;
#pragma unroll
      for (int dt = 0; dt < 4; ++dt)
        acc[m][dt] *= alpha;           // whole lane belongs to one q-row

      // P^T (C layout) -> lP rows q: b64 writes (4 packed k-values each)
      u16* Pw = &lP[w][0];
#pragma unroll
      for (int ct = 0; ct < 4; ++ct) {
        uint32_t d0 = (uint32_t)f2bf(sc[ct][0]) | ((uint32_t)f2bf(sc[ct][1]) << 16);
        uint32_t d1 = (uint32_t)f2bf(sc[ct][2]) | ((uint32_t)f2bf(sc[ct][3]) << 16);
        uint2 pk; pk.x = d0; pk.y = d1;
        *(uint2*)&Pw[l15 * 72 + ct * 16 + quad * 4] = pk;
      }
      __builtin_amdgcn_s_waitcnt(0xc07f);   // lgkmcnt(0)

      s16x8 ap0 = *(const s16x8*)&Pw[l15 * 72 + quad * 8];
      s16x8 ap1 = *(const s16x8*)&Pw[l15 * 72 + 32 + quad * 8];
#pragma unroll
      for (int dt = 0; dt < 4; ++dt) {
        s16x8 bv0 = *(const s16x8*)&cV[(dt * 16 + l15) * 64 + sw0];
        s16x8 bv1 = *(const s16x8*)&cV[(dt * 16 + l15) * 64 + sw1];
        acc[m][dt] = MFMA16x16x32(bv0, ap0, acc[m][dt], 0, 0, 0);
        acc[m][dt] = MFMA16x16x32(bv1, ap1, acc[m][dt], 0, 0, 0);
      }
    }
  }

  // epilogue: O = acc^T / l -> conc [B, S, H*D] bf16 (lane l15 = q-row)
#pragma unroll
  for (int m = 0; m < 2; ++m) {
    float inv = 1.0f / lrow[m];
    int qg = Q0m[m] + l15;
#pragma unroll
    for (int dt = 0; dt < 4; ++dt) {
      ushort4 o;
      o.x = f2bf(acc[m][dt][0] * inv);
      o.y = f2bf(acc[m][dt][1] * inv);
      o.z = f2bf(acc[m][dt][2] * inv);
      o.w = f2bf(acc[m][dt][3] * inv);
      *(ushort4*)&conc[((size_t)b * Sn + qg) * (Hn * Dn) + h * Dn + dt * 16 + quad * 4] = o;
    }
  }
}

// ---------------- launch ----------------
extern "C" void kernel_launch(void* const* d_in, const int* in_sizes, int n_in,
                              void* d_out, int out_size, void* d_ws, size_t ws_size,
                              hipStream_t stream)
{
  const float* x  = (const float*)d_in[0];
  const float* Wq = (const float*)d_in[1];
  const float* Wk = (const float*)d_in[2];
  const float* Wv = (const float*)d_in[3];
  const float* bq = (const float*)d_in[4];
  const float* bk = (const float*)d_in[5];
  const float* bv = (const float*)d_in[6];
  const float* Wo = (const float*)d_in[7];
  const float* bo = (const float*)d_in[8];
  float* out = (float*)d_out;

  char* p = (char*)d_ws;
  u16* xb    = (u16*)p; p += (size_t)Bn * Sn * En * sizeof(u16);
  u16* WallT = (u16*)p; p += (size_t)3 * Hn * Dn * En * sizeof(u16);
  u16* WoT   = (u16*)p; p += (size_t)En * Hn * Dn * sizeof(u16);
  float* biasA = (float*)p; p += (size_t)3 * Hn * Dn * sizeof(float);
  u16* Qb    = (u16*)p; p += (size_t)Bn * Hn * Sn * Dn * sizeof(u16);
  u16* Kb    = (u16*)p; p += (size_t)Bn * Hn * Sn * Dn * sizeof(u16);
  u16* Vt    = (u16*)p; p += (size_t)Bn * Hn * Dn * Sn * sizeof(u16);
  u16* conc  = (u16*)p; p += (size_t)Bn * Sn * Hn * Dn * sizeof(u16);

  int n4 = Bn * Sn * En / 4;
  cast_x_kernel<<<(n4 + 255) / 256, 256, 0, stream>>>((const float4*)x, (ushort4*)xb, n4);
  repack_qkv_w<<<3 * Hn * Dn, 256, 0, stream>>>(Wq, Wk, Wv, bq, bk, bv, WallT, biasA);
  repack_wo<<<En, 256, 0, stream>>>(Wo, WoT);

  // QKV: [8192,1024] x [1024,3072] -> Q/K direct, V^T via LDS transpose
  size_t smem0 = 128 * 64 * sizeof(u16) + 128 * 136 * sizeof(u16);  // lA+lB + lC
  gemm_bt<0><<<dim3(3 * Hn * Dn / 128, Bn * Sn / 128), 256, smem0, stream>>>(
      xb, WallT, biasA, Bn * Sn, 3 * Hn * Dn, En, Qb, Kb, Vt, nullptr);

  flash_attn<<<dim3(Sn / 128, Bn * Hn), 256, 0, stream>>>(Qb, Kb, Vt, conc);

  // out: [8192,1024] x [1024,1024] + bo -> fp32
  size_t smem1 = 128 * 64 * sizeof(u16);
  gemm_bt<1><<<dim3(En / 128, Bn * Sn / 128), 256, smem1, stream>>>(
      conc, WoT, bo, Bn * Sn, En, Hn * Dn, nullptr, nullptr, nullptr, out);
}